// Round 9
// baseline (135.017 us; speedup 1.0000x reference)
//
#include <hip/hip_runtime.h>
#include <hip/hip_bf16.h>
#include <math.h>

#define N_NODES 10000
#define N_EDGES 320000
#define IN_DIM  512
#define OUT_DIM 256
#define NEG_SLOPE 0.01f

typedef __attribute__((ext_vector_type(8))) short bf16x8;
typedef __attribute__((ext_vector_type(4))) float f32x4;

// ---------------- helpers ----------------
__device__ __forceinline__ unsigned int f2bf(float x) {
    unsigned int b = __float_as_uint(x);
    return (b + 0x7fffu + ((b >> 16) & 1u)) >> 16;   // round-to-nearest-even
}
__device__ __forceinline__ float bf2f(unsigned int u) {
    return __uint_as_float(u << 16);
}
// 8x f32 -> 8x bf16 via v_cvt_pk_bf16_f32 (RNE), 4 instructions
__device__ __forceinline__ bf16x8 cvt8(float4 a, float4 b) {
    union { bf16x8 v; unsigned int u[4]; } r;
    asm("v_cvt_pk_bf16_f32 %0, %1, %2" : "=v"(r.u[0]) : "v"(a.x), "v"(a.y));
    asm("v_cvt_pk_bf16_f32 %0, %1, %2" : "=v"(r.u[1]) : "v"(a.z), "v"(a.w));
    asm("v_cvt_pk_bf16_f32 %0, %1, %2" : "=v"(r.u[2]) : "v"(b.x), "v"(b.y));
    asm("v_cvt_pk_bf16_f32 %0, %1, %2" : "=v"(r.u[3]) : "v"(b.z), "v"(b.w));
    return r.v;
}

// ------ K1: MFMA GEMM from f32 operands (in-register bf16 cvt) + zero deg --
// blocks 0..1249: gemm tile (bx = b%625 row-tile, by = b/625 col-half).
//   block = 4 waves; wave: 16 rows x 32 cols, 2 accumulators.
// blocks 1250..1289: zero deg.
__global__ __launch_bounds__(256) void gemm_mfma(
    const float* __restrict__ A,     // h f32 [M][K]
    const float* __restrict__ B,     // fc_w f32 [N][K]
    const float* __restrict__ bias,  // [N]
    ushort* __restrict__ Zb,         // z bf16 [M][N]
    int* __restrict__ deg)
{
    const int blk = blockIdx.x;
    if (blk >= 1250) {
        int i = (blk - 1250) * 256 + threadIdx.x;
        if (i < N_NODES) deg[i] = 0;
        return;
    }
    const int K = IN_DIM;
    const int w = threadIdx.x >> 6;
    const int l = threadIdx.x & 63;
    const int lo = l & 15;
    const int hi = l >> 4;

    const int r0   = (blk % 625) * 16;             // 625 * 16 = 10000 exact
    const int colb = (blk / 625) * 128 + w * 32;   // 2 * 128 = 256 cols

    const float* Arow = A + (size_t)(r0 + lo) * K + hi * 8;
    const float* B0   = B + (size_t)(colb + 0  + lo) * K + hi * 8;
    const float* B1   = B + (size_t)(colb + 16 + lo) * K + hi * 8;

    f32x4 acc0 = {0.f, 0.f, 0.f, 0.f};
    f32x4 acc1 = {0.f, 0.f, 0.f, 0.f};

#pragma unroll
    for (int ks = 0; ks < IN_DIM / 32; ++ks) {
        const int k = ks * 32;
        float4 a0 = *(const float4*)(Arow + k);
        float4 a1 = *(const float4*)(Arow + k + 4);
        float4 p0 = *(const float4*)(B0 + k);
        float4 p1 = *(const float4*)(B0 + k + 4);
        float4 q0 = *(const float4*)(B1 + k);
        float4 q1 = *(const float4*)(B1 + k + 4);
        bf16x8 a  = cvt8(a0, a1);
        bf16x8 b0 = cvt8(p0, p1);
        bf16x8 b1 = cvt8(q0, q1);
        acc0 = __builtin_amdgcn_mfma_f32_16x16x32_bf16(a, b0, acc0, 0, 0, 0);
        acc1 = __builtin_amdgcn_mfma_f32_16x16x32_bf16(a, b1, acc1, 0, 0, 0);
    }

    // C/D layout: col = lane&15 (+16*frag), row = (lane>>4)*4 + i
    const int c0 = colb + lo;
    const float bv0 = bias[c0 + 0];
    const float bv1 = bias[c0 + 16];
#pragma unroll
    for (int i = 0; i < 4; ++i) {
        const int m = r0 + hi * 4 + i;
        ushort* zr = Zb + (size_t)m * OUT_DIM + c0;
        zr[0]  = (ushort)f2bf(acc0[i] + bv0);
        zr[16] = (ushort)f2bf(acc1[i] + bv1);
    }
}

// ---------- K2: fused {dst histogram, node attention dots} ----------
// blocks 0..312    : histogram (313*256*4 >= 320000 edges)
// blocks 313..2812 : node_dots (2500*4 = 10000 nodes, 1 wave/node)
#define HIST_BLOCKS 313
__global__ __launch_bounds__(256) void hist_dots(
    const int* __restrict__ dst, int* __restrict__ deg,
    const ushort* __restrict__ zb, const float* __restrict__ attn_w,
    const float* __restrict__ attn_b,
    float* __restrict__ s_src, float* __restrict__ s_dst)
{
    const int b = blockIdx.x;
    if (b < HIST_BLOCKS) {
        int i = b * 256 + threadIdx.x;   // edge group of 4
        if (i >= N_EDGES / 4) return;
        int4 d = *(const int4*)&dst[i * 4];
        atomicAdd(&deg[d.x], 1);
        atomicAdd(&deg[d.y], 1);
        atomicAdd(&deg[d.z], 1);
        atomicAdd(&deg[d.w], 1);
    } else {
        const int wid = threadIdx.x >> 6;
        const int lane = threadIdx.x & 63;
        const int n = (b - HIST_BLOCKS) * 4 + wid;
        if (n >= N_NODES) return;
        ushort4 q = *(const ushort4*)&zb[(size_t)n * OUT_DIM + lane * 4];
        float4 as = *(const float4*)&attn_w[lane * 4];
        float4 ad = *(const float4*)&attn_w[OUT_DIM + lane * 4];
        float z0 = bf2f(q.x), z1 = bf2f(q.y), z2 = bf2f(q.z), z3 = bf2f(q.w);
        float dsv = z0 * as.x + z1 * as.y + z2 * as.z + z3 * as.w;
        float ddv = z0 * ad.x + z1 * ad.y + z2 * ad.z + z3 * ad.w;
#pragma unroll
        for (int off = 32; off; off >>= 1) {
            dsv += __shfl_xor(dsv, off);
            ddv += __shfl_xor(ddv, off);
        }
        if (lane == 0) { s_src[n] = dsv; s_dst[n] = ddv + attn_b[0]; }
    }
}

// -------- K3: single-block exclusive scan: 10/thread; offsets + cursor ------
__global__ __launch_bounds__(1024) void scan_deg(
    const int* __restrict__ deg, int* __restrict__ offsets,
    int* __restrict__ cursor)
{
    const int t = threadIdx.x;
    const int lane = t & 63, wid = t >> 6;
    const int base = t * 10;

    int v[10];
    int tot = 0;
#pragma unroll
    for (int i = 0; i < 10; ++i) {
        int idx = base + i;
        v[i] = (idx < N_NODES) ? deg[idx] : 0;
        tot += v[i];
    }
    int sc = tot;
#pragma unroll
    for (int off = 1; off < 64; off <<= 1) {
        int u = __shfl_up(sc, off);
        if (lane >= off) sc += u;
    }
    __shared__ int wsum[16];
    if (lane == 63) wsum[wid] = sc;
    __syncthreads();
    int woff = 0;
    for (int ww = 0; ww < wid; ++ww) woff += wsum[ww];

    int run = woff + sc - tot;     // exclusive prefix for this thread
    if (t == 0) offsets[0] = 0;
#pragma unroll
    for (int i = 0; i < 10; ++i) {
        int idx = base + i;
        if (idx < N_NODES) cursor[idx] = run;   // CSR start = scatter cursor init
        run += v[i];
        if (idx < N_NODES) offsets[idx + 1] = run;
    }
}

// -------- K4: fused score + scatter into CSR order; 4 edges/thread ----------
__global__ __launch_bounds__(256) void scatter_edges(
    const int* __restrict__ src, const int* __restrict__ dst,
    const float* __restrict__ s_src, const float* __restrict__ s_dst,
    int* __restrict__ cursor, int2* __restrict__ rec)
{
    int i = blockIdx.x * 256 + threadIdx.x;
    if (i >= N_EDGES / 4) return;
    int4 s4 = *(const int4*)&src[i * 4];
    int4 d4 = *(const int4*)&dst[i * 4];
#pragma unroll
    for (int u = 0; u < 4; ++u) {
        int s = (u == 0) ? s4.x : (u == 1) ? s4.y : (u == 2) ? s4.z : s4.w;
        int d = (u == 0) ? d4.x : (u == 1) ? d4.y : (u == 2) ? d4.z : d4.w;
        float e = s_src[s] + s_dst[d];            // attn_b folded into s_dst
        e = (e >= 0.f) ? e : NEG_SLOPE * e;
        int pos = atomicAdd(&cursor[d], 1);
        rec[pos] = make_int2(s, __float_as_int(e));
    }
}

// -------- K5: softmax + weighted aggregation; 2 edges per wave-step ---------
// Wave = one node. Lanes split into halves; half p handles edge (j+p),
// each lane gathers 16B (8 cols) of its edge's z-row. 8 edges in flight.
__global__ __launch_bounds__(256) void aggregate(
    const ushort* __restrict__ zb, const int* __restrict__ offsets,
    const int2* __restrict__ rec, float* __restrict__ out)
{
    const int wid = threadIdx.x >> 6;
    const int lane = threadIdx.x & 63;
    const int half = lane >> 5;
    const int sl = lane & 31;
    const int n = blockIdx.x * 4 + wid;
    if (n >= N_NODES) return;
    const int beg = offsets[n], end = offsets[n + 1];

    float m = -INFINITY;
    for (int j = beg + lane; j < end; j += 64) m = fmaxf(m, __int_as_float(rec[j].y));
#pragma unroll
    for (int off = 32; off; off >>= 1) m = fmaxf(m, __shfl_xor(m, off));

    float den = 0.f;
    for (int j = beg + lane; j < end; j += 64) den += expf(__int_as_float(rec[j].y) - m);
#pragma unroll
    for (int off = 32; off; off >>= 1) den += __shfl_xor(den, off);
    float inv = (end > beg) ? 1.0f / den : 0.f;

    const int cbase = sl * 8;
    float acc[8] = {0.f, 0.f, 0.f, 0.f, 0.f, 0.f, 0.f, 0.f};

    int j = beg;
    for (; j + 8 <= end; j += 8) {
#pragma unroll
        for (int u = 0; u < 4; ++u) {
            int2 r = rec[j + 2 * u + half];
            float wgt = expf(__int_as_float(r.y) - m) * inv;
            bf16x8 q = *(const bf16x8*)&zb[(size_t)r.x * OUT_DIM + cbase];
#pragma unroll
            for (int c = 0; c < 8; ++c)
                acc[c] += wgt * bf2f((unsigned short)q[c]);
        }
    }
    for (; j < end; j += 2) {
        if (j + half < end) {
            int2 r = rec[j + half];
            float wgt = expf(__int_as_float(r.y) - m) * inv;
            bf16x8 q = *(const bf16x8*)&zb[(size_t)r.x * OUT_DIM + cbase];
#pragma unroll
            for (int c = 0; c < 8; ++c)
                acc[c] += wgt * bf2f((unsigned short)q[c]);
        }
    }
    // merge the two halves; then each lane stores 16B of the final row
#pragma unroll
    for (int c = 0; c < 8; ++c) acc[c] += __shfl_xor(acc[c], 32);
    f32x4 st;
    st[0] = acc[half * 4 + 0];
    st[1] = acc[half * 4 + 1];
    st[2] = acc[half * 4 + 2];
    st[3] = acc[half * 4 + 3];
    *(f32x4*)&out[(size_t)n * OUT_DIM + cbase + half * 4] = st;
}

extern "C" void kernel_launch(void* const* d_in, const int* in_sizes, int n_in,
                              void* d_out, int out_size, void* d_ws, size_t ws_size,
                              hipStream_t stream) {
    const float* h      = (const float*)d_in[0];
    const float* fc_w   = (const float*)d_in[1];
    const float* fc_b   = (const float*)d_in[2];
    const float* attn_w = (const float*)d_in[3];
    const float* attn_b = (const float*)d_in[4];
    const int*   src    = (const int*)d_in[5];
    const int*   dst    = (const int*)d_in[6];
    float* out = (float*)d_out;

    // workspace carve-up (all 16B-aligned)
    float* s_src   = (float*)d_ws;                    // 10000  @word 0
    float* s_dst   = s_src + N_NODES;                 // 10000  @word 10000
    int*   deg     = (int*)(s_dst + N_NODES);         // 10000  @word 20000
    int*   offsets = deg + N_NODES;                   // 10001  @word 30000
    int*   cursor  = offsets + N_NODES + 1;           // 10000  @word 40001
    int*   pad     = cursor + N_NODES;                // @word 50001, pad 3
    int2*  rec     = (int2*)(pad + 3);                // 320000 int2 @word 50004
    ushort* z_bf16 = (ushort*)(rec + N_EDGES);        // 2.56M ushort

    gemm_mfma<<<1290, 256, 0, stream>>>(h, fc_w, fc_b, z_bf16, deg);

    hist_dots<<<HIST_BLOCKS + 2500, 256, 0, stream>>>(dst, deg, z_bf16, attn_w, attn_b, s_src, s_dst);

    scan_deg<<<1, 1024, 0, stream>>>(deg, offsets, cursor);

    scatter_edges<<<(N_EDGES / 4 + 255) / 256, 256, 0, stream>>>(src, dst, s_src, s_dst, cursor, rec);

    aggregate<<<(N_NODES + 3) / 4, 256, 0, stream>>>(z_bf16, offsets, rec, out);
}

// Round 10
// 123.627 us; speedup vs baseline: 1.0921x; 1.0921x over previous
//
#include <hip/hip_runtime.h>
#include <hip/hip_bf16.h>
#include <math.h>

#define N_NODES 10000
#define N_EDGES 320000
#define IN_DIM  512
#define OUT_DIM 256
#define NEG_SLOPE 0.01f

typedef __attribute__((ext_vector_type(8))) short bf16x8;
typedef __attribute__((ext_vector_type(4))) float f32x4;

// ---------------- helpers ----------------
__device__ __forceinline__ unsigned int f2bf(float x) {
    unsigned int b = __float_as_uint(x);
    return (b + 0x7fffu + ((b >> 16) & 1u)) >> 16;   // round-to-nearest-even
}
__device__ __forceinline__ float bf2f(unsigned int u) {
    return __uint_as_float(u << 16);
}

// ---------- K1: fused {convert h, convert fc_w, zero deg} ----------
// blocks 0..2499   : h groups  (2500*256 = 640000 groups of 8 = 5.12M)
// blocks 2500..2563: fc_w groups (64*256 = 16384 groups of 8 = 131072)
// blocks 2564..2603: zero deg (40*256 >= 10000)
__global__ __launch_bounds__(256) void setup(
    const float* __restrict__ h, const float* __restrict__ fc_w,
    ushort* __restrict__ h_bf16, ushort* __restrict__ w_bf16,
    int* __restrict__ deg)
{
    const int b = blockIdx.x;
    const int t = threadIdx.x;
    if (b < 2500) {
        int i = b * 256 + t;
        const float* p = h + (size_t)i * 8;
        float4 v0 = *(const float4*)p;
        float4 v1 = *(const float4*)(p + 4);
        int4 o;
        o.x = (int)(f2bf(v0.x) | (f2bf(v0.y) << 16));
        o.y = (int)(f2bf(v0.z) | (f2bf(v0.w) << 16));
        o.z = (int)(f2bf(v1.x) | (f2bf(v1.y) << 16));
        o.w = (int)(f2bf(v1.z) | (f2bf(v1.w) << 16));
        *(int4*)(h_bf16 + (size_t)i * 8) = o;
    } else if (b < 2564) {
        int i = (b - 2500) * 256 + t;
        const float* p = fc_w + (size_t)i * 8;
        float4 v0 = *(const float4*)p;
        float4 v1 = *(const float4*)(p + 4);
        int4 o;
        o.x = (int)(f2bf(v0.x) | (f2bf(v0.y) << 16));
        o.y = (int)(f2bf(v0.z) | (f2bf(v0.w) << 16));
        o.z = (int)(f2bf(v1.x) | (f2bf(v1.y) << 16));
        o.w = (int)(f2bf(v1.z) | (f2bf(v1.w) << 16));
        *(int4*)(w_bf16 + (size_t)i * 8) = o;
    } else {
        int i = (b - 2564) * 256 + t;
        if (i < N_NODES) deg[i] = 0;
    }
}

// ------ K2: MFMA GEMM, max-TLP shape: wave = 16x16 tile, 1 accumulator -----
// grid 2500 blocks x 4 waves = 10000 waves (~9.8/SIMD).
// block b: rows (b>>2)*16, cols (b&3)*64; wave w: col strip w*16.
// Per iter: 2 x 16B loads : 1 MFMA. B (256KB bf16) is L2-resident.
__global__ __launch_bounds__(256) void gemm_mfma(
    const ushort* __restrict__ A,    // h bf16 [M][K]
    const ushort* __restrict__ B,    // fc_w bf16 [N][K]
    const float* __restrict__ bias,  // [N]
    ushort* __restrict__ Zb)         // z bf16 [M][N]
{
    const int K = IN_DIM;
    const int w = threadIdx.x >> 6;
    const int l = threadIdx.x & 63;
    const int lo = l & 15;
    const int hi = l >> 4;

    const int r0   = (blockIdx.x >> 2) * 16;          // 625*16 = 10000 exact
    const int colb = (blockIdx.x & 3) * 64 + w * 16;  // 16 strips of 16 cols

    const ushort* Arow = A + (size_t)(r0 + lo) * K + hi * 8;
    const ushort* Brow = B + (size_t)(colb + lo) * K + hi * 8;

    f32x4 acc = {0.f, 0.f, 0.f, 0.f};

#pragma unroll
    for (int ks = 0; ks < IN_DIM / 32; ++ks) {
        bf16x8 a = *(const bf16x8*)(Arow + ks * 32);
        bf16x8 b = *(const bf16x8*)(Brow + ks * 32);
        acc = __builtin_amdgcn_mfma_f32_16x16x32_bf16(a, b, acc, 0, 0, 0);
    }

    // C/D layout: col = lane&15, row = (lane>>4)*4 + i
    const int c0 = colb + lo;
    const float bv = bias[c0];
#pragma unroll
    for (int i = 0; i < 4; ++i) {
        const int m = r0 + hi * 4 + i;
        Zb[(size_t)m * OUT_DIM + c0] = (ushort)f2bf(acc[i] + bv);
    }
}

// ---------- K3: fused {dst histogram, node attention dots} ----------
// blocks 0..312    : histogram (313*256*4 >= 320000 edges)
// blocks 313..2812 : node_dots (2500*4 = 10000 nodes, 1 wave/node)
#define HIST_BLOCKS 313
__global__ __launch_bounds__(256) void hist_dots(
    const int* __restrict__ dst, int* __restrict__ deg,
    const ushort* __restrict__ zb, const float* __restrict__ attn_w,
    const float* __restrict__ attn_b,
    float* __restrict__ s_src, float* __restrict__ s_dst)
{
    const int b = blockIdx.x;
    if (b < HIST_BLOCKS) {
        int i = b * 256 + threadIdx.x;   // edge group of 4
        if (i >= N_EDGES / 4) return;
        int4 d = *(const int4*)&dst[i * 4];
        atomicAdd(&deg[d.x], 1);
        atomicAdd(&deg[d.y], 1);
        atomicAdd(&deg[d.z], 1);
        atomicAdd(&deg[d.w], 1);
    } else {
        const int wid = threadIdx.x >> 6;
        const int lane = threadIdx.x & 63;
        const int n = (b - HIST_BLOCKS) * 4 + wid;
        if (n >= N_NODES) return;
        ushort4 q = *(const ushort4*)&zb[(size_t)n * OUT_DIM + lane * 4];
        float4 as = *(const float4*)&attn_w[lane * 4];
        float4 ad = *(const float4*)&attn_w[OUT_DIM + lane * 4];
        float z0 = bf2f(q.x), z1 = bf2f(q.y), z2 = bf2f(q.z), z3 = bf2f(q.w);
        float dsv = z0 * as.x + z1 * as.y + z2 * as.z + z3 * as.w;
        float ddv = z0 * ad.x + z1 * ad.y + z2 * ad.z + z3 * ad.w;
#pragma unroll
        for (int off = 32; off; off >>= 1) {
            dsv += __shfl_xor(dsv, off);
            ddv += __shfl_xor(ddv, off);
        }
        if (lane == 0) { s_src[n] = dsv; s_dst[n] = ddv + attn_b[0]; }
    }
}

// -------- K4: single-block exclusive scan: 10/thread; offsets + cursor ------
__global__ __launch_bounds__(1024) void scan_deg(
    const int* __restrict__ deg, int* __restrict__ offsets,
    int* __restrict__ cursor)
{
    const int t = threadIdx.x;
    const int lane = t & 63, wid = t >> 6;
    const int base = t * 10;

    int v[10];
    int tot = 0;
#pragma unroll
    for (int i = 0; i < 10; ++i) {
        int idx = base + i;
        v[i] = (idx < N_NODES) ? deg[idx] : 0;
        tot += v[i];
    }
    int sc = tot;
#pragma unroll
    for (int off = 1; off < 64; off <<= 1) {
        int u = __shfl_up(sc, off);
        if (lane >= off) sc += u;
    }
    __shared__ int wsum[16];
    if (lane == 63) wsum[wid] = sc;
    __syncthreads();
    int woff = 0;
    for (int ww = 0; ww < wid; ++ww) woff += wsum[ww];

    int run = woff + sc - tot;     // exclusive prefix for this thread
    if (t == 0) offsets[0] = 0;
#pragma unroll
    for (int i = 0; i < 10; ++i) {
        int idx = base + i;
        if (idx < N_NODES) cursor[idx] = run;   // CSR start = scatter cursor init
        run += v[i];
        if (idx < N_NODES) offsets[idx + 1] = run;
    }
}

// -------- K5: fused score + scatter into CSR order; 4 edges/thread ----------
__global__ __launch_bounds__(256) void scatter_edges(
    const int* __restrict__ src, const int* __restrict__ dst,
    const float* __restrict__ s_src, const float* __restrict__ s_dst,
    int* __restrict__ cursor, int2* __restrict__ rec)
{
    int i = blockIdx.x * 256 + threadIdx.x;
    if (i >= N_EDGES / 4) return;
    int4 s4 = *(const int4*)&src[i * 4];
    int4 d4 = *(const int4*)&dst[i * 4];
#pragma unroll
    for (int u = 0; u < 4; ++u) {
        int s = (u == 0) ? s4.x : (u == 1) ? s4.y : (u == 2) ? s4.z : s4.w;
        int d = (u == 0) ? d4.x : (u == 1) ? d4.y : (u == 2) ? d4.z : d4.w;
        float e = s_src[s] + s_dst[d];            // attn_b folded into s_dst
        e = (e >= 0.f) ? e : NEG_SLOPE * e;
        int pos = atomicAdd(&cursor[d], 1);
        rec[pos] = make_int2(s, __float_as_int(e));
    }
}

// -------- K6: softmax + weighted aggregation; 2 edges per wave-step ---------
// Wave = one node. Lanes split into halves; half p handles edge (j+p),
// each lane gathers 16B (8 cols) of its edge's z-row. 8 edges in flight.
__global__ __launch_bounds__(256) void aggregate(
    const ushort* __restrict__ zb, const int* __restrict__ offsets,
    const int2* __restrict__ rec, float* __restrict__ out)
{
    const int wid = threadIdx.x >> 6;
    const int lane = threadIdx.x & 63;
    const int half = lane >> 5;
    const int sl = lane & 31;
    const int n = blockIdx.x * 4 + wid;
    if (n >= N_NODES) return;
    const int beg = offsets[n], end = offsets[n + 1];

    float m = -INFINITY;
    for (int j = beg + lane; j < end; j += 64) m = fmaxf(m, __int_as_float(rec[j].y));
#pragma unroll
    for (int off = 32; off; off >>= 1) m = fmaxf(m, __shfl_xor(m, off));

    float den = 0.f;
    for (int j = beg + lane; j < end; j += 64) den += expf(__int_as_float(rec[j].y) - m);
#pragma unroll
    for (int off = 32; off; off >>= 1) den += __shfl_xor(den, off);
    float inv = (end > beg) ? 1.0f / den : 0.f;

    const int cbase = sl * 8;
    float acc[8] = {0.f, 0.f, 0.f, 0.f, 0.f, 0.f, 0.f, 0.f};

    int j = beg;
    for (; j + 8 <= end; j += 8) {
#pragma unroll
        for (int u = 0; u < 4; ++u) {
            int2 r = rec[j + 2 * u + half];
            float wgt = expf(__int_as_float(r.y) - m) * inv;
            bf16x8 q = *(const bf16x8*)&zb[(size_t)r.x * OUT_DIM + cbase];
#pragma unroll
            for (int c = 0; c < 8; ++c)
                acc[c] += wgt * bf2f((unsigned short)q[c]);
        }
    }
    for (; j < end; j += 2) {
        if (j + half < end) {
            int2 r = rec[j + half];
            float wgt = expf(__int_as_float(r.y) - m) * inv;
            bf16x8 q = *(const bf16x8*)&zb[(size_t)r.x * OUT_DIM + cbase];
#pragma unroll
            for (int c = 0; c < 8; ++c)
                acc[c] += wgt * bf2f((unsigned short)q[c]);
        }
    }
    // merge the two halves; then each lane stores 16B of the final row
#pragma unroll
    for (int c = 0; c < 8; ++c) acc[c] += __shfl_xor(acc[c], 32);
    f32x4 st;
    st[0] = acc[half * 4 + 0];
    st[1] = acc[half * 4 + 1];
    st[2] = acc[half * 4 + 2];
    st[3] = acc[half * 4 + 3];
    *(f32x4*)&out[(size_t)n * OUT_DIM + cbase + half * 4] = st;
}

extern "C" void kernel_launch(void* const* d_in, const int* in_sizes, int n_in,
                              void* d_out, int out_size, void* d_ws, size_t ws_size,
                              hipStream_t stream) {
    const float* h      = (const float*)d_in[0];
    const float* fc_w   = (const float*)d_in[1];
    const float* fc_b   = (const float*)d_in[2];
    const float* attn_w = (const float*)d_in[3];
    const float* attn_b = (const float*)d_in[4];
    const int*   src    = (const int*)d_in[5];
    const int*   dst    = (const int*)d_in[6];
    float* out = (float*)d_out;

    // workspace carve-up (all 16B-aligned)
    float* s_src   = (float*)d_ws;                    // 10000  @word 0
    float* s_dst   = s_src + N_NODES;                 // 10000  @word 10000
    int*   deg     = (int*)(s_dst + N_NODES);         // 10000  @word 20000
    int*   offsets = deg + N_NODES;                   // 10001  @word 30000
    int*   cursor  = offsets + N_NODES + 1;           // 10000  @word 40001
    int*   pad     = cursor + N_NODES;                // @word 50001, pad 3
    int2*  rec     = (int2*)(pad + 3);                // 320000 int2
    ushort* z_bf16 = (ushort*)(rec + N_EDGES);        // 2.56M ushort
    ushort* w_bf16 = z_bf16 + (size_t)N_NODES * OUT_DIM; // 131072 ushort
    ushort* h_bf16 = w_bf16 + (size_t)OUT_DIM * IN_DIM;  // 5.12M ushort

    setup<<<2604, 256, 0, stream>>>(h, fc_w, h_bf16, w_bf16, deg);

    gemm_mfma<<<2500, 256, 0, stream>>>(h_bf16, w_bf16, fc_b, z_bf16);

    hist_dots<<<HIST_BLOCKS + 2500, 256, 0, stream>>>(dst, deg, z_bf16, attn_w, attn_b, s_src, s_dst);

    scan_deg<<<1, 1024, 0, stream>>>(deg, offsets, cursor);

    scatter_edges<<<(N_EDGES / 4 + 255) / 256, 256, 0, stream>>>(src, dst, s_src, s_dst, cursor, rec);

    aggregate<<<(N_NODES + 3) / 4, 256, 0, stream>>>(z_bf16, offsets, rec, out);
}

// Round 11
// 111.973 us; speedup vs baseline: 1.2058x; 1.1041x over previous
//
#include <hip/hip_runtime.h>
#include <hip/hip_bf16.h>
#include <math.h>

#define N_NODES 10000
#define N_EDGES 320000
#define IN_DIM  512
#define OUT_DIM 256
#define NEG_SLOPE 0.01f

typedef __attribute__((ext_vector_type(8))) short bf16x8;
typedef __attribute__((ext_vector_type(4))) float f32x4;

// ---------------- helpers ----------------
__device__ __forceinline__ unsigned int f2bf(float x) {
    unsigned int b = __float_as_uint(x);
    return (b + 0x7fffu + ((b >> 16) & 1u)) >> 16;   // round-to-nearest-even
}
__device__ __forceinline__ float bf2f(unsigned int u) {
    return __uint_as_float(u << 16);
}

// ---------- K1: fused {convert h, convert fc_w, zero deg} ----------
__global__ __launch_bounds__(256) void setup(
    const float* __restrict__ h, const float* __restrict__ fc_w,
    ushort* __restrict__ h_bf16, ushort* __restrict__ w_bf16,
    int* __restrict__ deg)
{
    const int b = blockIdx.x;
    const int t = threadIdx.x;
    if (b < 2500) {
        int i = b * 256 + t;
        const float* p = h + (size_t)i * 8;
        float4 v0 = *(const float4*)p;
        float4 v1 = *(const float4*)(p + 4);
        int4 o;
        o.x = (int)(f2bf(v0.x) | (f2bf(v0.y) << 16));
        o.y = (int)(f2bf(v0.z) | (f2bf(v0.w) << 16));
        o.z = (int)(f2bf(v1.x) | (f2bf(v1.y) << 16));
        o.w = (int)(f2bf(v1.z) | (f2bf(v1.w) << 16));
        *(int4*)(h_bf16 + (size_t)i * 8) = o;
    } else if (b < 2564) {
        int i = (b - 2500) * 256 + t;
        const float* p = fc_w + (size_t)i * 8;
        float4 v0 = *(const float4*)p;
        float4 v1 = *(const float4*)(p + 4);
        int4 o;
        o.x = (int)(f2bf(v0.x) | (f2bf(v0.y) << 16));
        o.y = (int)(f2bf(v0.z) | (f2bf(v0.w) << 16));
        o.z = (int)(f2bf(v1.x) | (f2bf(v1.y) << 16));
        o.w = (int)(f2bf(v1.z) | (f2bf(v1.w) << 16));
        *(int4*)(w_bf16 + (size_t)i * 8) = o;
    } else {
        int i = (b - 2564) * 256 + t;
        if (i < N_NODES) deg[i] = 0;
    }
}

// ------ K2: fused {MFMA GEMM (full-N block), dst histogram} ------
// blocks 0..624  : gemm. 512 thr = 8 waves; block = rows blk*16, ALL 256 cols.
//   wave w: cols w*32..w*32+31, 2 accumulators. A-tile (16KB) L1-shared by 8 waves
//   -> A read once chip-wide (10 MB); B (256KB bf16) L2-resident.
// blocks 625..781: histogram (157*512*4 >= 320000 edges).
#define GEMM_BLOCKS 625
__global__ __launch_bounds__(512) void gemm_hist(
    const ushort* __restrict__ A,    // h bf16 [M][K]
    const ushort* __restrict__ B,    // fc_w bf16 [N][K]
    const float* __restrict__ bias,  // [N]
    ushort* __restrict__ Zb,         // z bf16 [M][N]
    const int* __restrict__ dst, int* __restrict__ deg)
{
    const int blk = blockIdx.x;
    if (blk >= GEMM_BLOCKS) {
        int i = (blk - GEMM_BLOCKS) * 512 + threadIdx.x;   // edge group of 4
        if (i < N_EDGES / 4) {
            int4 d = *(const int4*)&dst[i * 4];
            atomicAdd(&deg[d.x], 1);
            atomicAdd(&deg[d.y], 1);
            atomicAdd(&deg[d.z], 1);
            atomicAdd(&deg[d.w], 1);
        }
        return;
    }
    const int K = IN_DIM;
    const int w = threadIdx.x >> 6;      // 0..7
    const int l = threadIdx.x & 63;
    const int lo = l & 15;
    const int hi = l >> 4;

    const int r0   = blk * 16;           // 625*16 = 10000 exact
    const int colb = w * 32;             // 8 waves cover 256 cols

    const ushort* Arow = A + (size_t)(r0 + lo) * K + hi * 8;
    const ushort* B0   = B + (size_t)(colb + 0  + lo) * K + hi * 8;
    const ushort* B1   = B + (size_t)(colb + 16 + lo) * K + hi * 8;

    f32x4 acc0 = {0.f, 0.f, 0.f, 0.f};
    f32x4 acc1 = {0.f, 0.f, 0.f, 0.f};

#pragma unroll
    for (int ks = 0; ks < IN_DIM / 32; ++ks) {
        bf16x8 a  = *(const bf16x8*)(Arow + ks * 32);
        bf16x8 b0 = *(const bf16x8*)(B0 + ks * 32);
        bf16x8 b1 = *(const bf16x8*)(B1 + ks * 32);
        acc0 = __builtin_amdgcn_mfma_f32_16x16x32_bf16(a, b0, acc0, 0, 0, 0);
        acc1 = __builtin_amdgcn_mfma_f32_16x16x32_bf16(a, b1, acc1, 0, 0, 0);
    }

    // C/D layout: col = lane&15 (+16*frag), row = (lane>>4)*4 + i
    const int c0 = colb + lo;
    const float bv0 = bias[c0 + 0];
    const float bv1 = bias[c0 + 16];
#pragma unroll
    for (int i = 0; i < 4; ++i) {
        const int m = r0 + hi * 4 + i;
        ushort* zr = Zb + (size_t)m * OUT_DIM + c0;
        zr[0]  = (ushort)f2bf(acc0[i] + bv0);
        zr[16] = (ushort)f2bf(acc1[i] + bv1);
    }
}

// ---------- K3: fused {node attention dots, deg exclusive scan} ----------
// blocks 0..1249 : dots, 8 nodes/block (wave/node).
// block 1250     : scan, 512 thr x 20 elems; writes offsets + cursor.
#define DOTS_BLOCKS 1250
__global__ __launch_bounds__(512) void dots_scan(
    const ushort* __restrict__ zb, const float* __restrict__ attn_w,
    const float* __restrict__ attn_b,
    float* __restrict__ s_src, float* __restrict__ s_dst,
    const int* __restrict__ deg, int* __restrict__ offsets,
    int* __restrict__ cursor)
{
    const int blk = blockIdx.x;
    const int t = threadIdx.x;
    if (blk < DOTS_BLOCKS) {
        const int wid = t >> 6;
        const int lane = t & 63;
        const int n = blk * 8 + wid;
        if (n >= N_NODES) return;
        ushort4 q = *(const ushort4*)&zb[(size_t)n * OUT_DIM + lane * 4];
        float4 as = *(const float4*)&attn_w[lane * 4];
        float4 ad = *(const float4*)&attn_w[OUT_DIM + lane * 4];
        float z0 = bf2f(q.x), z1 = bf2f(q.y), z2 = bf2f(q.z), z3 = bf2f(q.w);
        float dsv = z0 * as.x + z1 * as.y + z2 * as.z + z3 * as.w;
        float ddv = z0 * ad.x + z1 * ad.y + z2 * ad.z + z3 * ad.w;
#pragma unroll
        for (int off = 32; off; off >>= 1) {
            dsv += __shfl_xor(dsv, off);
            ddv += __shfl_xor(ddv, off);
        }
        if (lane == 0) { s_src[n] = dsv; s_dst[n] = ddv + attn_b[0]; }
        return;
    }
    // ---- scan block ----
    const int lane = t & 63, wid = t >> 6;   // 8 waves
    const int base = t * 20;
    int v[20];
    int tot = 0;
#pragma unroll
    for (int i = 0; i < 20; ++i) {
        int idx = base + i;
        v[i] = (idx < N_NODES) ? deg[idx] : 0;
        tot += v[i];
    }
    int sc = tot;
#pragma unroll
    for (int off = 1; off < 64; off <<= 1) {
        int u = __shfl_up(sc, off);
        if (lane >= off) sc += u;
    }
    __shared__ int wsum[8];
    if (lane == 63) wsum[wid] = sc;
    __syncthreads();
    int woff = 0;
    for (int ww = 0; ww < wid; ++ww) woff += wsum[ww];

    int run = woff + sc - tot;     // exclusive prefix for this thread
    if (t == 0) offsets[0] = 0;
#pragma unroll
    for (int i = 0; i < 20; ++i) {
        int idx = base + i;
        if (idx < N_NODES) cursor[idx] = run;   // CSR start = scatter cursor init
        run += v[i];
        if (idx < N_NODES) offsets[idx + 1] = run;
    }
}

// -------- K4: fused score + scatter into CSR order; 4 edges/thread ----------
__global__ __launch_bounds__(256) void scatter_edges(
    const int* __restrict__ src, const int* __restrict__ dst,
    const float* __restrict__ s_src, const float* __restrict__ s_dst,
    int* __restrict__ cursor, int2* __restrict__ rec)
{
    int i = blockIdx.x * 256 + threadIdx.x;
    if (i >= N_EDGES / 4) return;
    int4 s4 = *(const int4*)&src[i * 4];
    int4 d4 = *(const int4*)&dst[i * 4];
#pragma unroll
    for (int u = 0; u < 4; ++u) {
        int s = (u == 0) ? s4.x : (u == 1) ? s4.y : (u == 2) ? s4.z : s4.w;
        int d = (u == 0) ? d4.x : (u == 1) ? d4.y : (u == 2) ? d4.z : d4.w;
        float e = s_src[s] + s_dst[d];            // attn_b folded into s_dst
        e = (e >= 0.f) ? e : NEG_SLOPE * e;
        int pos = atomicAdd(&cursor[d], 1);
        rec[pos] = make_int2(s, __float_as_int(e));
    }
}

// -------- K5: softmax + weighted aggregation; 2 edges per wave-step ---------
__global__ __launch_bounds__(256) void aggregate(
    const ushort* __restrict__ zb, const int* __restrict__ offsets,
    const int2* __restrict__ rec, float* __restrict__ out)
{
    const int wid = threadIdx.x >> 6;
    const int lane = threadIdx.x & 63;
    const int half = lane >> 5;
    const int sl = lane & 31;
    const int n = blockIdx.x * 4 + wid;
    if (n >= N_NODES) return;
    const int beg = offsets[n], end = offsets[n + 1];

    float m = -INFINITY;
    for (int j = beg + lane; j < end; j += 64) m = fmaxf(m, __int_as_float(rec[j].y));
#pragma unroll
    for (int off = 32; off; off >>= 1) m = fmaxf(m, __shfl_xor(m, off));

    float den = 0.f;
    for (int j = beg + lane; j < end; j += 64) den += expf(__int_as_float(rec[j].y) - m);
#pragma unroll
    for (int off = 32; off; off >>= 1) den += __shfl_xor(den, off);
    float inv = (end > beg) ? 1.0f / den : 0.f;

    const int cbase = sl * 8;
    float acc[8] = {0.f, 0.f, 0.f, 0.f, 0.f, 0.f, 0.f, 0.f};

    int j = beg;
    for (; j + 8 <= end; j += 8) {
#pragma unroll
        for (int u = 0; u < 4; ++u) {
            int2 r = rec[j + 2 * u + half];
            float wgt = expf(__int_as_float(r.y) - m) * inv;
            bf16x8 q = *(const bf16x8*)&zb[(size_t)r.x * OUT_DIM + cbase];
#pragma unroll
            for (int c = 0; c < 8; ++c)
                acc[c] += wgt * bf2f((unsigned short)q[c]);
        }
    }
    for (; j < end; j += 2) {
        if (j + half < end) {
            int2 r = rec[j + half];
            float wgt = expf(__int_as_float(r.y) - m) * inv;
            bf16x8 q = *(const bf16x8*)&zb[(size_t)r.x * OUT_DIM + cbase];
#pragma unroll
            for (int c = 0; c < 8; ++c)
                acc[c] += wgt * bf2f((unsigned short)q[c]);
        }
    }
#pragma unroll
    for (int c = 0; c < 8; ++c) acc[c] += __shfl_xor(acc[c], 32);
    f32x4 st;
    st[0] = acc[half * 4 + 0];
    st[1] = acc[half * 4 + 1];
    st[2] = acc[half * 4 + 2];
    st[3] = acc[half * 4 + 3];
    *(f32x4*)&out[(size_t)n * OUT_DIM + cbase + half * 4] = st;
}

extern "C" void kernel_launch(void* const* d_in, const int* in_sizes, int n_in,
                              void* d_out, int out_size, void* d_ws, size_t ws_size,
                              hipStream_t stream) {
    const float* h      = (const float*)d_in[0];
    const float* fc_w   = (const float*)d_in[1];
    const float* fc_b   = (const float*)d_in[2];
    const float* attn_w = (const float*)d_in[3];
    const float* attn_b = (const float*)d_in[4];
    const int*   src    = (const int*)d_in[5];
    const int*   dst    = (const int*)d_in[6];
    float* out = (float*)d_out;

    // workspace carve-up (all 16B-aligned)
    float* s_src   = (float*)d_ws;                    // 10000  @word 0
    float* s_dst   = s_src + N_NODES;                 // 10000  @word 10000
    int*   deg     = (int*)(s_dst + N_NODES);         // 10000  @word 20000
    int*   offsets = deg + N_NODES;                   // 10001  @word 30000
    int*   cursor  = offsets + N_NODES + 1;           // 10000  @word 40001
    int*   pad     = cursor + N_NODES;                // @word 50001, pad 3
    int2*  rec     = (int2*)(pad + 3);                // 320000 int2
    ushort* z_bf16 = (ushort*)(rec + N_EDGES);        // 2.56M ushort
    ushort* w_bf16 = z_bf16 + (size_t)N_NODES * OUT_DIM; // 131072 ushort
    ushort* h_bf16 = w_bf16 + (size_t)OUT_DIM * IN_DIM;  // 5.12M ushort

    setup<<<2604, 256, 0, stream>>>(h, fc_w, h_bf16, w_bf16, deg);

    gemm_hist<<<GEMM_BLOCKS + 157, 512, 0, stream>>>(h_bf16, w_bf16, fc_b, z_bf16, dst, deg);

    dots_scan<<<DOTS_BLOCKS + 1, 512, 0, stream>>>(z_bf16, attn_w, attn_b, s_src, s_dst, deg, offsets, cursor);

    scatter_edges<<<(N_EDGES / 4 + 255) / 256, 256, 0, stream>>>(src, dst, s_src, s_dst, cursor, rec);

    aggregate<<<(N_NODES + 3) / 4, 256, 0, stream>>>(z_bf16, offsets, rec, out);
}

// Round 12
// 101.777 us; speedup vs baseline: 1.3266x; 1.1002x over previous
//
#include <hip/hip_runtime.h>
#include <hip/hip_bf16.h>
#include <math.h>

#define N_NODES 10000
#define N_EDGES 320000
#define IN_DIM  512
#define OUT_DIM 256
#define NEG_SLOPE 0.01f

typedef __attribute__((ext_vector_type(8))) short bf16x8;
typedef __attribute__((ext_vector_type(4))) float f32x4;

// ---------------- helpers ----------------
__device__ __forceinline__ unsigned int f2bf(float x) {
    unsigned int b = __float_as_uint(x);
    return (b + 0x7fffu + ((b >> 16) & 1u)) >> 16;   // round-to-nearest-even
}
__device__ __forceinline__ float bf2f(unsigned int u) {
    return __uint_as_float(u << 16);
}

// Packed fragment layout for X[R][K=512] (R multiple of 16):
//   group-of-8 g covers row m = g>>6, k8 = (g&63)*8.
//   rg = m>>4, lo = m&15, ks = (g&63)>>2, hi = (g&63)&3.
//   packed slot index = ((rg*16 + ks)*64 + hi*16 + lo)   (each slot = 8 bf16 = 16B)
// A wave's MFMA fragment for (rg, ks) is then slots [ (rg*16+ks)*64 + l ] — one
// contiguous 1KB read across 64 lanes.

// ---------- K1: fused {pack h, pack fc_w, zero deg} ----------
__global__ __launch_bounds__(256) void setup(
    const float* __restrict__ h, const float* __restrict__ fc_w,
    ushort* __restrict__ h_pk, ushort* __restrict__ w_pk,
    int* __restrict__ deg)
{
    const int b = blockIdx.x;
    const int t = threadIdx.x;
    if (b < 2500) {
        int i = b * 256 + t;                 // group-of-8 over h
        const float* p = h + (size_t)i * 8;
        float4 v0 = *(const float4*)p;
        float4 v1 = *(const float4*)(p + 4);
        int4 o;
        o.x = (int)(f2bf(v0.x) | (f2bf(v0.y) << 16));
        o.y = (int)(f2bf(v0.z) | (f2bf(v0.w) << 16));
        o.z = (int)(f2bf(v1.x) | (f2bf(v1.y) << 16));
        o.w = (int)(f2bf(v1.z) | (f2bf(v1.w) << 16));
        int m  = i >> 6;
        int kg = i & 63;
        size_t slot = ((size_t)((m >> 4) * 16 + (kg >> 2)) * 64) + (kg & 3) * 16 + (m & 15);
        *(int4*)(h_pk + slot * 8) = o;
    } else if (b < 2564) {
        int i = (b - 2500) * 256 + t;        // group-of-8 over fc_w
        const float* p = fc_w + (size_t)i * 8;
        float4 v0 = *(const float4*)p;
        float4 v1 = *(const float4*)(p + 4);
        int4 o;
        o.x = (int)(f2bf(v0.x) | (f2bf(v0.y) << 16));
        o.y = (int)(f2bf(v0.z) | (f2bf(v0.w) << 16));
        o.z = (int)(f2bf(v1.x) | (f2bf(v1.y) << 16));
        o.w = (int)(f2bf(v1.z) | (f2bf(v1.w) << 16));
        int n  = i >> 6;
        int kg = i & 63;
        size_t slot = ((size_t)((n >> 4) * 16 + (kg >> 2)) * 64) + (kg & 3) * 16 + (n & 15);
        *(int4*)(w_pk + slot * 8) = o;
    } else {
        int i = (b - 2564) * 256 + t;
        if (i < N_NODES) deg[i] = 0;
    }
}

// ------ K2: fused {MFMA GEMM on packed operands, dst histogram} ------
// blocks 0..624: gemm. 512 thr = 8 waves; block = rows blk*16, ALL 256 cols.
//   wave w: cols w*32 (2 col-frags). Every operand load = contiguous 1KB.
// blocks 625..781: histogram (157*512*4 >= 320000 edges).
#define GEMM_BLOCKS 625
__global__ __launch_bounds__(512) void gemm_hist(
    const ushort* __restrict__ Apk,  // h packed  [625][16][64 slots]
    const ushort* __restrict__ Bpk,  // fc_w packed [16][16][64 slots]
    const float* __restrict__ bias,  // [N]
    ushort* __restrict__ Zb,         // z bf16 [M][N]
    const int* __restrict__ dst, int* __restrict__ deg)
{
    const int blk = blockIdx.x;
    if (blk >= GEMM_BLOCKS) {
        int i = (blk - GEMM_BLOCKS) * 512 + threadIdx.x;   // edge group of 4
        if (i < N_EDGES / 4) {
            int4 d = *(const int4*)&dst[i * 4];
            atomicAdd(&deg[d.x], 1);
            atomicAdd(&deg[d.y], 1);
            atomicAdd(&deg[d.z], 1);
            atomicAdd(&deg[d.w], 1);
        }
        return;
    }
    const int w = threadIdx.x >> 6;      // 0..7
    const int l = threadIdx.x & 63;
    const int lo = l & 15;
    const int hi = l >> 4;

    const int r0   = blk * 16;           // 625*16 = 10000 exact
    const int colb = w * 32;             // 8 waves cover 256 cols

    // packed bases (in ushort units; one (rg|fc, ks) frame = 64 slots * 8 = 512)
    const ushort* Ab = Apk + (size_t)blk * 16 * 512 + l * 8;
    const ushort* B0 = Bpk + (size_t)(w * 2 + 0) * 16 * 512 + l * 8;
    const ushort* B1 = Bpk + (size_t)(w * 2 + 1) * 16 * 512 + l * 8;

    f32x4 acc0 = {0.f, 0.f, 0.f, 0.f};
    f32x4 acc1 = {0.f, 0.f, 0.f, 0.f};

#pragma unroll
    for (int ks = 0; ks < IN_DIM / 32; ++ks) {
        bf16x8 a  = *(const bf16x8*)(Ab + ks * 512);
        bf16x8 b0 = *(const bf16x8*)(B0 + ks * 512);
        bf16x8 b1 = *(const bf16x8*)(B1 + ks * 512);
        acc0 = __builtin_amdgcn_mfma_f32_16x16x32_bf16(a, b0, acc0, 0, 0, 0);
        acc1 = __builtin_amdgcn_mfma_f32_16x16x32_bf16(a, b1, acc1, 0, 0, 0);
    }

    // C/D layout: col = lane&15 (+16*frag), row = (lane>>4)*4 + i
    const int c0 = colb + lo;
    const float bv0 = bias[c0 + 0];
    const float bv1 = bias[c0 + 16];
#pragma unroll
    for (int i = 0; i < 4; ++i) {
        const int m = r0 + hi * 4 + i;
        ushort* zr = Zb + (size_t)m * OUT_DIM + c0;
        zr[0]  = (ushort)f2bf(acc0[i] + bv0);
        zr[16] = (ushort)f2bf(acc1[i] + bv1);
    }
}

// ---------- K3: fused {node attention dots, deg exclusive scan} ----------
#define DOTS_BLOCKS 1250
__global__ __launch_bounds__(512) void dots_scan(
    const ushort* __restrict__ zb, const float* __restrict__ attn_w,
    const float* __restrict__ attn_b,
    float* __restrict__ s_src, float* __restrict__ s_dst,
    const int* __restrict__ deg, int* __restrict__ offsets,
    int* __restrict__ cursor)
{
    const int blk = blockIdx.x;
    const int t = threadIdx.x;
    if (blk < DOTS_BLOCKS) {
        const int wid = t >> 6;
        const int lane = t & 63;
        const int n = blk * 8 + wid;
        if (n >= N_NODES) return;
        ushort4 q = *(const ushort4*)&zb[(size_t)n * OUT_DIM + lane * 4];
        float4 as = *(const float4*)&attn_w[lane * 4];
        float4 ad = *(const float4*)&attn_w[OUT_DIM + lane * 4];
        float z0 = bf2f(q.x), z1 = bf2f(q.y), z2 = bf2f(q.z), z3 = bf2f(q.w);
        float dsv = z0 * as.x + z1 * as.y + z2 * as.z + z3 * as.w;
        float ddv = z0 * ad.x + z1 * ad.y + z2 * ad.z + z3 * ad.w;
#pragma unroll
        for (int off = 32; off; off >>= 1) {
            dsv += __shfl_xor(dsv, off);
            ddv += __shfl_xor(ddv, off);
        }
        if (lane == 0) { s_src[n] = dsv; s_dst[n] = ddv + attn_b[0]; }
        return;
    }
    // ---- scan block ----
    const int lane = t & 63, wid = t >> 6;   // 8 waves
    const int base = t * 20;
    int v[20];
    int tot = 0;
#pragma unroll
    for (int i = 0; i < 20; ++i) {
        int idx = base + i;
        v[i] = (idx < N_NODES) ? deg[idx] : 0;
        tot += v[i];
    }
    int sc = tot;
#pragma unroll
    for (int off = 1; off < 64; off <<= 1) {
        int u = __shfl_up(sc, off);
        if (lane >= off) sc += u;
    }
    __shared__ int wsum[8];
    if (lane == 63) wsum[wid] = sc;
    __syncthreads();
    int woff = 0;
    for (int ww = 0; ww < wid; ++ww) woff += wsum[ww];

    int run = woff + sc - tot;     // exclusive prefix for this thread
    if (t == 0) offsets[0] = 0;
#pragma unroll
    for (int i = 0; i < 20; ++i) {
        int idx = base + i;
        if (idx < N_NODES) cursor[idx] = run;   // CSR start = scatter cursor init
        run += v[i];
        if (idx < N_NODES) offsets[idx + 1] = run;
    }
}

// -------- K4: fused score + scatter into CSR order; 4 edges/thread ----------
__global__ __launch_bounds__(256) void scatter_edges(
    const int* __restrict__ src, const int* __restrict__ dst,
    const float* __restrict__ s_src, const float* __restrict__ s_dst,
    int* __restrict__ cursor, int2* __restrict__ rec)
{
    int i = blockIdx.x * 256 + threadIdx.x;
    if (i >= N_EDGES / 4) return;
    int4 s4 = *(const int4*)&src[i * 4];
    int4 d4 = *(const int4*)&dst[i * 4];
#pragma unroll
    for (int u = 0; u < 4; ++u) {
        int s = (u == 0) ? s4.x : (u == 1) ? s4.y : (u == 2) ? s4.z : s4.w;
        int d = (u == 0) ? d4.x : (u == 1) ? d4.y : (u == 2) ? d4.z : d4.w;
        float e = s_src[s] + s_dst[d];            // attn_b folded into s_dst
        e = (e >= 0.f) ? e : NEG_SLOPE * e;
        int pos = atomicAdd(&cursor[d], 1);
        rec[pos] = make_int2(s, __float_as_int(e));
    }
}

// -------- K5: softmax + weighted aggregation; 2 edges per wave-step ---------
__global__ __launch_bounds__(256) void aggregate(
    const ushort* __restrict__ zb, const int* __restrict__ offsets,
    const int2* __restrict__ rec, float* __restrict__ out)
{
    const int wid = threadIdx.x >> 6;
    const int lane = threadIdx.x & 63;
    const int half = lane >> 5;
    const int sl = lane & 31;
    const int n = blockIdx.x * 4 + wid;
    if (n >= N_NODES) return;
    const int beg = offsets[n], end = offsets[n + 1];

    float m = -INFINITY;
    for (int j = beg + lane; j < end; j += 64) m = fmaxf(m, __int_as_float(rec[j].y));
#pragma unroll
    for (int off = 32; off; off >>= 1) m = fmaxf(m, __shfl_xor(m, off));

    float den = 0.f;
    for (int j = beg + lane; j < end; j += 64) den += expf(__int_as_float(rec[j].y) - m);
#pragma unroll
    for (int off = 32; off; off >>= 1) den += __shfl_xor(den, off);
    float inv = (end > beg) ? 1.0f / den : 0.f;

    const int cbase = sl * 8;
    float acc[8] = {0.f, 0.f, 0.f, 0.f, 0.f, 0.f, 0.f, 0.f};

    int j = beg;
    for (; j + 8 <= end; j += 8) {
#pragma unroll
        for (int u = 0; u < 4; ++u) {
            int2 r = rec[j + 2 * u + half];
            float wgt = expf(__int_as_float(r.y) - m) * inv;
            bf16x8 q = *(const bf16x8*)&zb[(size_t)r.x * OUT_DIM + cbase];
#pragma unroll
            for (int c = 0; c < 8; ++c)
                acc[c] += wgt * bf2f((unsigned short)q[c]);
        }
    }
    for (; j < end; j += 2) {
        if (j + half < end) {
            int2 r = rec[j + half];
            float wgt = expf(__int_as_float(r.y) - m) * inv;
            bf16x8 q = *(const bf16x8*)&zb[(size_t)r.x * OUT_DIM + cbase];
#pragma unroll
            for (int c = 0; c < 8; ++c)
                acc[c] += wgt * bf2f((unsigned short)q[c]);
        }
    }
#pragma unroll
    for (int c = 0; c < 8; ++c) acc[c] += __shfl_xor(acc[c], 32);
    f32x4 st;
    st[0] = acc[half * 4 + 0];
    st[1] = acc[half * 4 + 1];
    st[2] = acc[half * 4 + 2];
    st[3] = acc[half * 4 + 3];
    *(f32x4*)&out[(size_t)n * OUT_DIM + cbase + half * 4] = st;
}

extern "C" void kernel_launch(void* const* d_in, const int* in_sizes, int n_in,
                              void* d_out, int out_size, void* d_ws, size_t ws_size,
                              hipStream_t stream) {
    const float* h      = (const float*)d_in[0];
    const float* fc_w   = (const float*)d_in[1];
    const float* fc_b   = (const float*)d_in[2];
    const float* attn_w = (const float*)d_in[3];
    const float* attn_b = (const float*)d_in[4];
    const int*   src    = (const int*)d_in[5];
    const int*   dst    = (const int*)d_in[6];
    float* out = (float*)d_out;

    // workspace carve-up (all 16B-aligned)
    float* s_src   = (float*)d_ws;                    // 10000  @word 0
    float* s_dst   = s_src + N_NODES;                 // 10000  @word 10000
    int*   deg     = (int*)(s_dst + N_NODES);         // 10000  @word 20000
    int*   offsets = deg + N_NODES;                   // 10001  @word 30000
    int*   cursor  = offsets + N_NODES + 1;           // 10000  @word 40001
    int*   pad     = cursor + N_NODES;                // @word 50001, pad 3
    int2*  rec     = (int2*)(pad + 3);                // 320000 int2
    ushort* z_bf16 = (ushort*)(rec + N_EDGES);        // 2.56M ushort
    ushort* w_pk   = z_bf16 + (size_t)N_NODES * OUT_DIM; // 131072 ushort (packed)
    ushort* h_pk   = w_pk + (size_t)OUT_DIM * IN_DIM;    // 5.12M ushort (packed)

    setup<<<2604, 256, 0, stream>>>(h, fc_w, h_pk, w_pk, deg);

    gemm_hist<<<GEMM_BLOCKS + 157, 512, 0, stream>>>(h_pk, w_pk, fc_b, z_bf16, dst, deg);

    dots_scan<<<DOTS_BLOCKS + 1, 512, 0, stream>>>(z_bf16, attn_w, attn_b, s_src, s_dst, deg, offsets, cursor);

    scatter_edges<<<(N_EDGES / 4 + 255) / 256, 256, 0, stream>>>(src, dst, s_src, s_dst, cursor, rec);

    aggregate<<<(N_NODES + 3) / 4, 256, 0, stream>>>(z_bf16, offsets, rec, out);
}

// Round 13
// 98.646 us; speedup vs baseline: 1.3687x; 1.0317x over previous
//
#include <hip/hip_runtime.h>
#include <hip/hip_bf16.h>
#include <math.h>

#define N_NODES 10000
#define N_EDGES 320000
#define IN_DIM  512
#define OUT_DIM 256
#define NEG_SLOPE 0.01f

typedef __attribute__((ext_vector_type(8))) short bf16x8;
typedef __attribute__((ext_vector_type(4))) float f32x4;

// ---------------- helpers ----------------
__device__ __forceinline__ unsigned int f2bf(float x) {
    unsigned int b = __float_as_uint(x);
    return (b + 0x7fffu + ((b >> 16) & 1u)) >> 16;   // round-to-nearest-even
}
__device__ __forceinline__ float bf2f(unsigned int u) {
    return __uint_as_float(u << 16);
}

// Packed fragment layout for fc_w[N=256][K=512]:
//   group-of-8 g: row n = g>>6, kg = g&63; slot = ((n>>4)*16 + (kg>>2))*64 + (kg&3)*16 + (n&15)
//   -> a wave's B-fragment (col-frag, ks) is one contiguous 1KB read.

// ---------- K1: pack fc_w + zero deg (52 blocks x 512) ----------
__global__ __launch_bounds__(512) void prep(
    const float* __restrict__ fc_w, ushort* __restrict__ w_pk,
    int* __restrict__ deg)
{
    const int b = blockIdx.x;
    const int t = threadIdx.x;
    if (b < 32) {
        int i = b * 512 + t;                 // group-of-8 over fc_w (16384 total)
        const float* p = fc_w + (size_t)i * 8;
        float4 v0 = *(const float4*)p;
        float4 v1 = *(const float4*)(p + 4);
        int4 o;
        o.x = (int)(f2bf(v0.x) | (f2bf(v0.y) << 16));
        o.y = (int)(f2bf(v0.z) | (f2bf(v0.w) << 16));
        o.z = (int)(f2bf(v1.x) | (f2bf(v1.y) << 16));
        o.w = (int)(f2bf(v1.z) | (f2bf(v1.w) << 16));
        int n  = i >> 6;
        int kg = i & 63;
        size_t slot = ((size_t)((n >> 4) * 16 + (kg >> 2)) * 64) + (kg & 3) * 16 + (n & 15);
        *(int4*)(w_pk + slot * 8) = o;
    } else {
        int i = (b - 32) * 512 + t;
        if (i < N_NODES) deg[i] = 0;
    }
}

// ------ K2: fused {MFMA GEMM (A staged in LDS from f32 h), dst histogram} ---
// blocks 0..624: gemm. 512 thr = 8 waves; block = rows blk*16, ALL 256 cols.
//   A: coalesced f32 read -> in-register bf16 -> XOR-swizzled LDS tile (16KB).
//   B: packed w_pk, contiguous 1KB fragment loads (L2-resident).
// blocks 625..781: histogram (157*512*4 >= 320000 edges).
#define GEMM_BLOCKS 625
__global__ __launch_bounds__(512) void gemm_hist(
    const float* __restrict__ h,     // h f32 [M][K]
    const ushort* __restrict__ Bpk,  // fc_w packed
    const float* __restrict__ bias,  // [N]
    ushort* __restrict__ Zb,         // z bf16 [M][N]
    const int* __restrict__ dst, int* __restrict__ deg)
{
    const int blk = blockIdx.x;
    if (blk >= GEMM_BLOCKS) {
        int i = (blk - GEMM_BLOCKS) * 512 + threadIdx.x;   // edge group of 4
        if (i < N_EDGES / 4) {
            int4 d = *(const int4*)&dst[i * 4];
            atomicAdd(&deg[d.x], 1);
            atomicAdd(&deg[d.y], 1);
            atomicAdd(&deg[d.z], 1);
            atomicAdd(&deg[d.w], 1);
        }
        return;
    }
    __shared__ ushort As[16 * IN_DIM];   // 16KB: row-major rows 0..15, XOR-swizzled
    const int t = threadIdx.x;
    const int r0 = blk * 16;             // 625*16 = 10000 exact
    {
        // stage: thread t -> row t>>5, 16-col group (t&31); 64B f32 -> 32B bf16
        const int row = t >> 5;
        const int c16 = t & 31;
        const float* p = h + (size_t)(r0 + row) * IN_DIM + c16 * 16;
        float4 v0 = *(const float4*)(p + 0);
        float4 v1 = *(const float4*)(p + 4);
        float4 v2 = *(const float4*)(p + 8);
        float4 v3 = *(const float4*)(p + 12);
        int4 o0, o1;
        o0.x = (int)(f2bf(v0.x) | (f2bf(v0.y) << 16));
        o0.y = (int)(f2bf(v0.z) | (f2bf(v0.w) << 16));
        o0.z = (int)(f2bf(v1.x) | (f2bf(v1.y) << 16));
        o0.w = (int)(f2bf(v1.z) | (f2bf(v1.w) << 16));
        o1.x = (int)(f2bf(v2.x) | (f2bf(v2.y) << 16));
        o1.y = (int)(f2bf(v2.z) | (f2bf(v2.w) << 16));
        o1.z = (int)(f2bf(v3.x) | (f2bf(v3.y) << 16));
        o1.w = (int)(f2bf(v3.z) | (f2bf(v3.w) << 16));
        const int swz = (row & 7) << 4;
        char* base = (char*)As;
        *(int4*)(base + ((row * 1024 + (c16 * 2 + 0) * 16) ^ swz)) = o0;
        *(int4*)(base + ((row * 1024 + (c16 * 2 + 1) * 16) ^ swz)) = o1;
    }
    __syncthreads();

    const int w = t >> 6;      // 0..7
    const int l = t & 63;
    const int lo = l & 15;
    const int hi = l >> 4;
    const int colb = w * 32;

    const ushort* B0 = Bpk + (size_t)(w * 2 + 0) * 16 * 512 + l * 8;
    const ushort* B1 = Bpk + (size_t)(w * 2 + 1) * 16 * 512 + l * 8;
    const char* Ab = (const char*)As;
    const int aswz = (lo & 7) << 4;
    const int abase = lo * 1024 + hi * 16;

    f32x4 acc0 = {0.f, 0.f, 0.f, 0.f};
    f32x4 acc1 = {0.f, 0.f, 0.f, 0.f};

#pragma unroll
    for (int ks = 0; ks < IN_DIM / 32; ++ks) {
        bf16x8 a  = *(const bf16x8*)(Ab + ((abase + ks * 64) ^ aswz));
        bf16x8 b0 = *(const bf16x8*)(B0 + ks * 512);
        bf16x8 b1 = *(const bf16x8*)(B1 + ks * 512);
        acc0 = __builtin_amdgcn_mfma_f32_16x16x32_bf16(a, b0, acc0, 0, 0, 0);
        acc1 = __builtin_amdgcn_mfma_f32_16x16x32_bf16(a, b1, acc1, 0, 0, 0);
    }

    // C/D layout: col = lane&15 (+16*frag), row = (lane>>4)*4 + i
    const int c0 = colb + lo;
    const float bv0 = bias[c0 + 0];
    const float bv1 = bias[c0 + 16];
#pragma unroll
    for (int i = 0; i < 4; ++i) {
        const int m = r0 + hi * 4 + i;
        ushort* zr = Zb + (size_t)m * OUT_DIM + c0;
        zr[0]  = (ushort)f2bf(acc0[i] + bv0);
        zr[16] = (ushort)f2bf(acc1[i] + bv1);
    }
}

// ---------- K3: fused {node attention dots, deg exclusive scan} ----------
#define DOTS_BLOCKS 1250
__global__ __launch_bounds__(512) void dots_scan(
    const ushort* __restrict__ zb, const float* __restrict__ attn_w,
    const float* __restrict__ attn_b,
    float* __restrict__ s_src, float* __restrict__ s_dst,
    const int* __restrict__ deg, int* __restrict__ offsets,
    int* __restrict__ cursor)
{
    const int blk = blockIdx.x;
    const int t = threadIdx.x;
    if (blk < DOTS_BLOCKS) {
        const int wid = t >> 6;
        const int lane = t & 63;
        const int n = blk * 8 + wid;
        if (n >= N_NODES) return;
        ushort4 q = *(const ushort4*)&zb[(size_t)n * OUT_DIM + lane * 4];
        float4 as = *(const float4*)&attn_w[lane * 4];
        float4 ad = *(const float4*)&attn_w[OUT_DIM + lane * 4];
        float z0 = bf2f(q.x), z1 = bf2f(q.y), z2 = bf2f(q.z), z3 = bf2f(q.w);
        float dsv = z0 * as.x + z1 * as.y + z2 * as.z + z3 * as.w;
        float ddv = z0 * ad.x + z1 * ad.y + z2 * ad.z + z3 * ad.w;
#pragma unroll
        for (int off = 32; off; off >>= 1) {
            dsv += __shfl_xor(dsv, off);
            ddv += __shfl_xor(ddv, off);
        }
        if (lane == 0) { s_src[n] = dsv; s_dst[n] = ddv + attn_b[0]; }
        return;
    }
    // ---- scan block ----
    const int lane = t & 63, wid = t >> 6;   // 8 waves
    const int base = t * 20;
    int v[20];
    int tot = 0;
#pragma unroll
    for (int i = 0; i < 20; ++i) {
        int idx = base + i;
        v[i] = (idx < N_NODES) ? deg[idx] : 0;
        tot += v[i];
    }
    int sc = tot;
#pragma unroll
    for (int off = 1; off < 64; off <<= 1) {
        int u = __shfl_up(sc, off);
        if (lane >= off) sc += u;
    }
    __shared__ int wsum[8];
    if (lane == 63) wsum[wid] = sc;
    __syncthreads();
    int woff = 0;
    for (int ww = 0; ww < wid; ++ww) woff += wsum[ww];

    int run = woff + sc - tot;     // exclusive prefix for this thread
    if (t == 0) offsets[0] = 0;
#pragma unroll
    for (int i = 0; i < 20; ++i) {
        int idx = base + i;
        if (idx < N_NODES) cursor[idx] = run;   // CSR start = scatter cursor init
        run += v[i];
        if (idx < N_NODES) offsets[idx + 1] = run;
    }
}

// -------- K4: fused score + scatter into CSR order; 4 edges/thread ----------
__global__ __launch_bounds__(256) void scatter_edges(
    const int* __restrict__ src, const int* __restrict__ dst,
    const float* __restrict__ s_src, const float* __restrict__ s_dst,
    int* __restrict__ cursor, int2* __restrict__ rec)
{
    int i = blockIdx.x * 256 + threadIdx.x;
    if (i >= N_EDGES / 4) return;
    int4 s4 = *(const int4*)&src[i * 4];
    int4 d4 = *(const int4*)&dst[i * 4];
#pragma unroll
    for (int u = 0; u < 4; ++u) {
        int s = (u == 0) ? s4.x : (u == 1) ? s4.y : (u == 2) ? s4.z : s4.w;
        int d = (u == 0) ? d4.x : (u == 1) ? d4.y : (u == 2) ? d4.z : d4.w;
        float e = s_src[s] + s_dst[d];            // attn_b folded into s_dst
        e = (e >= 0.f) ? e : NEG_SLOPE * e;
        int pos = atomicAdd(&cursor[d], 1);
        rec[pos] = make_int2(s, __float_as_int(e));
    }
}

// -------- K5: softmax + weighted aggregation; 2 edges per wave-step ---------
__global__ __launch_bounds__(256) void aggregate(
    const ushort* __restrict__ zb, const int* __restrict__ offsets,
    const int2* __restrict__ rec, float* __restrict__ out)
{
    const int wid = threadIdx.x >> 6;
    const int lane = threadIdx.x & 63;
    const int half = lane >> 5;
    const int sl = lane & 31;
    const int n = blockIdx.x * 4 + wid;
    if (n >= N_NODES) return;
    const int beg = offsets[n], end = offsets[n + 1];

    float m = -INFINITY;
    for (int j = beg + lane; j < end; j += 64) m = fmaxf(m, __int_as_float(rec[j].y));
#pragma unroll
    for (int off = 32; off; off >>= 1) m = fmaxf(m, __shfl_xor(m, off));

    float den = 0.f;
    for (int j = beg + lane; j < end; j += 64) den += expf(__int_as_float(rec[j].y) - m);
#pragma unroll
    for (int off = 32; off; off >>= 1) den += __shfl_xor(den, off);
    float inv = (end > beg) ? 1.0f / den : 0.f;

    const int cbase = sl * 8;
    float acc[8] = {0.f, 0.f, 0.f, 0.f, 0.f, 0.f, 0.f, 0.f};

    int j = beg;
    for (; j + 8 <= end; j += 8) {
#pragma unroll
        for (int u = 0; u < 4; ++u) {
            int2 r = rec[j + 2 * u + half];
            float wgt = expf(__int_as_float(r.y) - m) * inv;
            bf16x8 q = *(const bf16x8*)&zb[(size_t)r.x * OUT_DIM + cbase];
#pragma unroll
            for (int c = 0; c < 8; ++c)
                acc[c] += wgt * bf2f((unsigned short)q[c]);
        }
    }
    for (; j < end; j += 2) {
        if (j + half < end) {
            int2 r = rec[j + half];
            float wgt = expf(__int_as_float(r.y) - m) * inv;
            bf16x8 q = *(const bf16x8*)&zb[(size_t)r.x * OUT_DIM + cbase];
#pragma unroll
            for (int c = 0; c < 8; ++c)
                acc[c] += wgt * bf2f((unsigned short)q[c]);
        }
    }
#pragma unroll
    for (int c = 0; c < 8; ++c) acc[c] += __shfl_xor(acc[c], 32);
    f32x4 st;
    st[0] = acc[half * 4 + 0];
    st[1] = acc[half * 4 + 1];
    st[2] = acc[half * 4 + 2];
    st[3] = acc[half * 4 + 3];
    *(f32x4*)&out[(size_t)n * OUT_DIM + cbase + half * 4] = st;
}

extern "C" void kernel_launch(void* const* d_in, const int* in_sizes, int n_in,
                              void* d_out, int out_size, void* d_ws, size_t ws_size,
                              hipStream_t stream) {
    const float* h      = (const float*)d_in[0];
    const float* fc_w   = (const float*)d_in[1];
    const float* fc_b   = (const float*)d_in[2];
    const float* attn_w = (const float*)d_in[3];
    const float* attn_b = (const float*)d_in[4];
    const int*   src    = (const int*)d_in[5];
    const int*   dst    = (const int*)d_in[6];
    float* out = (float*)d_out;

    // workspace carve-up (all 16B-aligned)
    float* s_src   = (float*)d_ws;                    // 10000  @word 0
    float* s_dst   = s_src + N_NODES;                 // 10000  @word 10000
    int*   deg     = (int*)(s_dst + N_NODES);         // 10000  @word 20000
    int*   offsets = deg + N_NODES;                   // 10001  @word 30000
    int*   cursor  = offsets + N_NODES + 1;           // 10000  @word 40001
    int*   pad     = cursor + N_NODES;                // @word 50001, pad 3
    int2*  rec     = (int2*)(pad + 3);                // 320000 int2
    ushort* z_bf16 = (ushort*)(rec + N_EDGES);        // 2.56M ushort
    ushort* w_pk   = z_bf16 + (size_t)N_NODES * OUT_DIM; // 131072 ushort (packed)

    prep<<<52, 512, 0, stream>>>(fc_w, w_pk, deg);

    gemm_hist<<<GEMM_BLOCKS + 157, 512, 0, stream>>>(h, w_pk, fc_b, z_bf16, dst, deg);

    dots_scan<<<DOTS_BLOCKS + 1, 512, 0, stream>>>(z_bf16, attn_w, attn_b, s_src, s_dst, deg, offsets, cursor);

    scatter_edges<<<(N_EDGES / 4 + 255) / 256, 256, 0, stream>>>(src, dst, s_src, s_dst, cursor, rec);

    aggregate<<<(N_NODES + 3) / 4, 256, 0, stream>>>(z_bf16, offsets, rec, out);
}